// Round 1
// baseline (347.043 us; speedup 1.0000x reference)
//
#include <hip/hip_runtime.h>
#include <stdint.h>

#define N_NODES 50000
#define N_EDGES 625000
#define DIN 256
#define HD 128
#define LN_EPS 1e-5f
#define AGG_LD 132   // f32 agg leading dim: 128 + 4 pad -> 2-way banks on frag read

typedef __attribute__((ext_vector_type(8))) short bvec8;
typedef __attribute__((ext_vector_type(4))) float fvec4;

__device__ inline float bf2f(ushort u){
  union { uint32_t u32; float f; } c; c.u32 = ((uint32_t)u) << 16; return c.f;
}
__device__ inline ushort f2bf(float f){
  union { float f; uint32_t u; } c; c.f = f;
  uint32_t u = c.u;
  return (ushort)((u + 0x7fffu + ((u >> 16) & 1u)) >> 16);
}
__device__ inline float rdany(const void* p, int i, int f32){
  return f32 ? ((const float*)p)[i] : bf2f(((const ushort*)p)[i]);
}

// ---------------- zero + dtype probe (merged) ----------------
__global__ void k_zero_probe(const ushort* __restrict__ x, int* __restrict__ flag,
                             int* cnt, int* cursor, int* total){
  if ((int)blockIdx.x == (int)gridDim.x - 1){
    __shared__ int red[256];
    int t = threadIdx.x;
    int c = 0;
    for (int j = 0; j < 8; j++){
      ushort u = x[t * 8 + j];
      int e = (u >> 7) & 0xff;
      if (e >= 0x88 || (e != 0 && e <= 0x70)) c++;
    }
    red[t] = c;
    __syncthreads();
    for (int off = 128; off > 0; off >>= 1){
      if (t < off) red[t] += red[t + off];
      __syncthreads();
    }
    if (t == 0) flag[0] = (red[0] > 100) ? 1 : 0;
    return;
  }
  int i = blockIdx.x * 256 + threadIdx.x;
  if (i < N_NODES){ cnt[i] = 0; cursor[i] = 0; }
  if (i == 0) total[0] = 0;
}

// ---------------- CSR build ----------------
__global__ void k_count(const int* __restrict__ dst, int* __restrict__ cnt){
  int e = blockIdx.x * 256 + threadIdx.x;
  if (e < N_EDGES) atomicAdd(&cnt[dst[e]], 1);
}

__global__ void k_assign(const int* __restrict__ cnt, int* __restrict__ rowstart,
                         int* __restrict__ total){
  int i = blockIdx.x * 256 + threadIdx.x;
  int lane = threadIdx.x & 63;
  int c = (i < N_NODES) ? cnt[i] : 0;
  int scan = c;
  #pragma unroll
  for (int m = 1; m < 64; m <<= 1){
    int v = __shfl_up(scan, m, 64);
    if (lane >= m) scan += v;
  }
  int wave_total = __shfl(scan, 63, 64);
  int base = 0;
  if (lane == 63) base = atomicAdd(total, wave_total);
  base = __shfl(base, 63, 64);
  if (i < N_NODES) rowstart[i] = base + scan - c;
}

__global__ void k_fill(const int* __restrict__ src, const int* __restrict__ dst,
                       const int* __restrict__ rowstart, int* __restrict__ cursor,
                       int* __restrict__ esrc){
  int e = blockIdx.x * 256 + threadIdx.x;
  if (e < N_EDGES){
    int d = dst[e];
    int pos = atomicAdd(&cursor[d], 1);
    esrc[rowstart[d] + pos] = src[e];
  }
}

// ---------------- weight prep: swizzle into MFMA fragment order ----------------
// chunk c = k0*8 + t; lane l's 8 elems are B-frag (n = t*16+(l&15), k = k0*32+(l>>4)*8+j)
__global__ void k_prep_w(const int* __restrict__ flag,
                         const void* __restrict__ W_in,
                         const void* __restrict__ Wl1, const void* __restrict__ Wr1,
                         const void* __restrict__ Wl2, const void* __restrict__ Wr2,
                         ushort* __restrict__ WtA, ushort* __restrict__ Wc1, ushort* __restrict__ Wc2,
                         const void* b_in, const void* kind_embed, const void* ext_seed,
                         const void* bl1, const void* gammap, const void* betap,
                         const void* bl2, float* __restrict__ vecs){
  int f32 = flag[0];
  int idx = blockIdx.x * 256 + threadIdx.x;
  if (idx < 128 * 256){
    int c   = idx >> 9;
    int lam = (idx >> 3) & 63;
    int j   = idx & 7;
    int k0  = c >> 3;
    int t   = c & 7;
    int n   = t * 16 + (lam & 15);
    int k   = k0 * 32 + (lam >> 4) * 8 + j;
    WtA[idx] = f2bf(rdany(W_in, k * 128 + n, f32));
    if (k < 128){
      Wc1[idx] = f2bf(rdany(Wl1, k * 128 + n, f32));
      Wc2[idx] = f2bf(rdany(Wl2, k * 128 + n, f32));
    } else {
      Wc1[idx] = f2bf(rdany(Wr1, (k - 128) * 128 + n, f32));
      Wc2[idx] = f2bf(rdany(Wr2, (k - 128) * 128 + n, f32));
    }
  }
  if (blockIdx.x == 0){
    for (int i = threadIdx.x; i < 1152; i += 256){
      float v;
      if (i < 128)       v = rdany(b_in, i, f32);
      else if (i < 512)  v = rdany(kind_embed, i - 128, f32);
      else if (i < 640)  v = rdany(ext_seed, i - 512, f32);
      else if (i < 768)  v = rdany(bl1, i - 640, f32);
      else if (i < 896)  v = rdany(gammap, i - 768, f32);
      else if (i < 1024) v = rdany(betap, i - 896, f32);
      else               v = rdany(bl2, i - 1024, f32);
      vecs[i] = v;
    }
  }
}

// ---------------- input GEMM: LDS-staged B ----------------
__global__ void __launch_bounds__(256) k_gemm_in(
    const int* __restrict__ flag, const void* __restrict__ xin,
    const ushort* __restrict__ WtA, const float* __restrict__ vecs,
    const int* __restrict__ node_kind, ushort* __restrict__ h0){
  __shared__ __align__(16) ushort sW[128 * 256];
  int f32 = flag[0];
  int tid  = threadIdx.x;
  int wave = tid >> 6;
  int lane = tid & 63;
  int quad = lane >> 4;
  int l16  = lane & 15;
  int rb = blockIdx.x * 64 + wave * 16;

  fvec4 acc[8];
  #pragma unroll
  for (int t = 0; t < 8; t++)
    #pragma unroll
    for (int i = 0; i < 4; i++) acc[t][i] = 0.f;

  int arow = rb + l16; if (arow >= N_NODES) arow = N_NODES - 1;
  const ushort* abf = (const ushort*)xin + (size_t)arow * DIN + quad * 8;
  const float*  af  = (const float*)xin + (size_t)arow * DIN + quad * 8;

  bvec8 a[8];
  if (f32){
    #pragma unroll
    for (int k0 = 0; k0 < 8; k0++){
      fvec4 lo = *(const fvec4*)(af + k0 * 32);
      fvec4 hi = *(const fvec4*)(af + k0 * 32 + 4);
      a[k0][0] = (short)f2bf(lo[0]); a[k0][1] = (short)f2bf(lo[1]);
      a[k0][2] = (short)f2bf(lo[2]); a[k0][3] = (short)f2bf(lo[3]);
      a[k0][4] = (short)f2bf(hi[0]); a[k0][5] = (short)f2bf(hi[1]);
      a[k0][6] = (short)f2bf(hi[2]); a[k0][7] = (short)f2bf(hi[3]);
    }
  } else {
    #pragma unroll
    for (int k0 = 0; k0 < 8; k0++) a[k0] = *(const bvec8*)(abf + k0 * 32);
  }

  #pragma unroll
  for (int it = 0; it < 16; it++){
    int off = it * 2048 + tid * 8;
    *(uint4*)(sW + off) = *(const uint4*)(WtA + off);
  }
  __syncthreads();

  #pragma unroll
  for (int k0 = 0; k0 < 8; k0++){
    #pragma unroll
    for (int t = 0; t < 8; t++){
      bvec8 b = *(const bvec8*)(sW + ((k0 * 8 + t) * 64 + lane) * 8);
      acc[t] = __builtin_amdgcn_mfma_f32_16x16x32_bf16(a[k0], b, acc[t], 0, 0, 0);
    }
  }

  const float* b_in  = vecs;
  const float* kinde = vecs + 128;
  const float* ext   = vecs + 512;
  #pragma unroll
  for (int i = 0; i < 4; i++){
    int row = rb + quad * 4 + i;
    if (row >= N_NODES) continue;
    int kind = node_kind[row];
    float extf = (kind != 0) ? 1.f : 0.f;
    #pragma unroll
    for (int t = 0; t < 8; t++){
      int col = t * 16 + l16;
      float v = acc[t][i] + b_in[col] + kinde[kind * HD + col] + extf * ext[col];
      h0[(size_t)row * HD + col] = f2bf(v);
    }
  }
}

// ---------------- fused gather + conv GEMM ----------------
// Phase 1 (NEW): the block's 64 nodes own a contiguous CSR edge range
// (rowstart is monotone within each 64-aligned group by construction of
// k_assign). Split that range into 16 equal chunks, one per quad; each quad
// streams its chunk 8 edges at a time (8x16B loads in flight per lane),
// accumulates the current dst-run in registers, and flushes via LDS f32
// atomicAdd on dst change. Perfect load balance, uniform pipelineable trip
// counts, 2x MLP vs the old node-owned loop.
// Phase 2: agg A-frags from f32 LDS (scaled by 1/deg), then the same 32KB
// LDS is reused for the weights in two half-stages.
template<int MODE>
__global__ void __launch_bounds__(256, 4) k_conv_fused(
    const int* __restrict__ flag, const ushort* __restrict__ h,
    const int* __restrict__ rowstart, const int* __restrict__ cnt,
    const int* __restrict__ esrc,
    const ushort* __restrict__ Wc, const float* __restrict__ vecs,
    void* __restrict__ outp){
  __shared__ __align__(16) float sAgg[64 * AGG_LD];   // 33792 B, reused for weights
  __shared__ int rs[65];
  ushort* sW = (ushort*)sAgg;
  int f32 = flag[0];
  int tid  = threadIdx.x;
  int wave = tid >> 6;
  int lane = tid & 63;
  int quad = lane >> 4;
  int l16  = lane & 15;
  int rb0 = blockIdx.x * 64;
  int rb  = rb0 + wave * 16;

  // stage CSR row starts for this block's 64 nodes (+ end sentinel)
  if (tid < 65){
    int v;
    if (tid == 64){
      int ln = (rb0 + 63 < N_NODES) ? rb0 + 63 : N_NODES - 1;
      v = rowstart[ln] + cnt[ln];
    } else {
      int node = rb0 + tid;
      v = (node < N_NODES) ? rowstart[node]
                           : rowstart[N_NODES - 1] + cnt[N_NODES - 1];
    }
    rs[tid] = v;
  }
  for (int o = tid; o < 64 * AGG_LD; o += 256) sAgg[o] = 0.f;

  // self-row (h-half) A-frags: issue global loads early
  int arow = rb + l16; if (arow >= N_NODES) arow = N_NODES - 1;
  const ushort* hb = h + (size_t)arow * HD + quad * 8;
  bvec8 a[8];
  #pragma unroll
  for (int j = 0; j < 4; j++) a[4 + j] = *(const bvec8*)(hb + j * 32);

  __syncthreads();

  // ---- phase 1: edge-chunked gather ----
  int e0 = rs[0], e1 = rs[64];
  int nE = e1 - e0;
  int q = tid >> 4;                 // quad id 0..15 within block
  int chunk = (nE + 15) >> 4;
  int ce0 = e0 + q * chunk;
  int ce1 = ce0 + chunk; if (ce1 > e1) ce1 = e1;
  if (ce0 < ce1){
    // largest d in [0,63] with rs[d] <= ce0  (rs[0]=e0 <= ce0 < e1 = rs[64])
    int lo = 0, hi = 64;
    while (lo + 1 < hi){ int mid = (lo + hi) >> 1; if (rs[mid] <= ce0) lo = mid; else hi = mid; }
    int d = lo;
    int dnext = rs[d + 1];
    float acc[8];
    #pragma unroll
    for (int jj = 0; jj < 8; jj++) acc[jj] = 0.f;
    for (int e = ce0; e < ce1; e += 8){
      int idx[8];
      #pragma unroll
      for (int k = 0; k < 8; k++){
        int ee = e + k;
        idx[k] = esrc[ee < ce1 ? ee : ce1 - 1];
      }
      uint4 r[8];
      #pragma unroll
      for (int k = 0; k < 8; k++)
        r[k] = *(const uint4*)(h + (size_t)idx[k] * HD + l16 * 8);
      #pragma unroll
      for (int k = 0; k < 8; k++){
        if (e + k < ce1){
          while (e + k >= dnext){          // dst run ended: flush + advance
            float* p = sAgg + d * AGG_LD + l16 * 8;
            #pragma unroll
            for (int jj = 0; jj < 8; jj++){ atomicAdd(p + jj, acc[jj]); acc[jj] = 0.f; }
            d++; dnext = rs[d + 1];
          }
          const uint32_t* w = (const uint32_t*)&r[k];
          #pragma unroll
          for (int jj = 0; jj < 4; jj++){
            acc[2*jj]   += bf2f((ushort)(w[jj] & 0xffffu));
            acc[2*jj+1] += bf2f((ushort)(w[jj] >> 16));
          }
        }
      }
    }
    float* p = sAgg + d * AGG_LD + l16 * 8;   // final flush
    #pragma unroll
    for (int jj = 0; jj < 8; jj++) atomicAdd(p + jj, acc[jj]);
  }
  __syncthreads();

  // ---- agg A-frags from f32 LDS (scale by 1/deg) ----
  {
    int nd = wave * 16 + l16;
    int deg = rs[nd + 1] - rs[nd];
    float scale = (deg > 0) ? 1.f / (float)deg : 0.f;
    const float* ap = sAgg + nd * AGG_LD + quad * 8;
    #pragma unroll
    for (int k0 = 0; k0 < 4; k0++){
      #pragma unroll
      for (int jj = 0; jj < 8; jj++)
        a[k0][jj] = (short)f2bf(ap[k0 * 32 + jj] * scale);
    }
  }
  __syncthreads();   // everyone done reading agg before overwrite

  fvec4 acc[8];
  #pragma unroll
  for (int t = 0; t < 8; t++)
    #pragma unroll
    for (int i = 0; i < 4; i++) acc[t][i] = 0.f;

  // ---- weights in two 32KB half-stages over the same LDS ----
  #pragma unroll
  for (int s = 0; s < 2; s++){
    #pragma unroll
    for (int it = 0; it < 8; it++){
      int off = it * 2048 + tid * 8;
      *(uint4*)(sW + off) = *(const uint4*)(Wc + s * 16384 + off);
    }
    __syncthreads();
    #pragma unroll
    for (int k0 = 0; k0 < 4; k0++){
      #pragma unroll
      for (int t = 0; t < 8; t++){
        bvec8 b = *(const bvec8*)(sW + ((k0 * 8 + t) * 64 + lane) * 8);
        acc[t] = __builtin_amdgcn_mfma_f32_16x16x32_bf16(a[s * 4 + k0], b, acc[t], 0, 0, 0);
      }
    }
    __syncthreads();
  }

  if (MODE == 1){
    const float* bias   = vecs + 640;
    const float* gammav = vecs + 768;
    const float* betav  = vecs + 896;
    float zv[8][4];
    float s1[4] = {0.f, 0.f, 0.f, 0.f};
    float s2[4] = {0.f, 0.f, 0.f, 0.f};
    #pragma unroll
    for (int t = 0; t < 8; t++){
      float bc = bias[t * 16 + l16];
      #pragma unroll
      for (int i = 0; i < 4; i++){
        float v = acc[t][i] + bc;
        zv[t][i] = v;
        s1[i] += v;
        s2[i] += v * v;
      }
    }
    #pragma unroll
    for (int m = 1; m < 16; m <<= 1){
      #pragma unroll
      for (int i = 0; i < 4; i++){
        s1[i] += __shfl_xor(s1[i], m, 64);
        s2[i] += __shfl_xor(s2[i], m, 64);
      }
    }
    float mu[4], rsv[4];
    #pragma unroll
    for (int i = 0; i < 4; i++){
      mu[i] = s1[i] * (1.f / 128.f);
      float var = s2[i] * (1.f / 128.f) - mu[i] * mu[i];
      rsv[i] = rsqrtf(var + LN_EPS);
    }
    ushort* ob = (ushort*)outp;
    #pragma unroll
    for (int t = 0; t < 8; t++){
      int col = t * 16 + l16;
      float g = gammav[col], bt = betav[col];
      #pragma unroll
      for (int i = 0; i < 4; i++){
        int row = rb + quad * 4 + i;
        if (row >= N_NODES) continue;
        float v = (zv[t][i] - mu[i]) * rsv[i] * g + bt;
        v = fmaxf(v, 0.f);
        ob[(size_t)row * HD + col] = f2bf(v);
      }
    }
  } else {
    const float* bias = vecs + 1024;
    #pragma unroll
    for (int t = 0; t < 8; t++){
      int col = t * 16 + l16;
      float bc = bias[col];
      #pragma unroll
      for (int i = 0; i < 4; i++){
        int row = rb + quad * 4 + i;
        if (row >= N_NODES) continue;
        float v = acc[t][i] + bc;
        if (f32) ((float*)outp)[(size_t)row * HD + col] = v;
        else     ((ushort*)outp)[(size_t)row * HD + col] = f2bf(v);
      }
    }
  }
}

extern "C" void kernel_launch(void* const* d_in, const int* in_sizes, int n_in,
                              void* d_out, int out_size, void* d_ws, size_t ws_size,
                              hipStream_t stream) {
  const void* x          = d_in[0];
  const int*  ei         = (const int*)d_in[1];
  const int*  node_kind  = (const int*)d_in[2];
  const void* W_in       = d_in[3];
  const void* b_in       = d_in[4];
  const void* kind_embed = d_in[5];
  const void* ext_seed   = d_in[6];
  const void* Wl1        = d_in[7];
  const void* bl1        = d_in[8];
  const void* Wr1        = d_in[9];
  const void* gammap     = d_in[10];
  const void* betap      = d_in[11];
  const void* Wl2        = d_in[12];
  const void* bl2        = d_in[13];
  const void* Wr2        = d_in[14];
  const int* src = ei;
  const int* dst = ei + N_EDGES;

  char* ws = (char*)d_ws;
  size_t off = 0;
  auto alloc = [&](size_t bytes) -> void* {
    void* p = ws + off;
    off += (bytes + 255) & ~(size_t)255;
    return p;
  };
  int*    flag     = (int*)alloc(256);
  int*    total    = (int*)alloc(256);
  int*    cnt      = (int*)alloc(N_NODES * 4);
  int*    cursor   = (int*)alloc(N_NODES * 4);
  int*    rowstart = (int*)alloc(N_NODES * 4);
  int*    esrc     = (int*)alloc(N_EDGES * 4);
  ushort* WtA      = (ushort*)alloc(128 * 256 * 2);
  ushort* Wc1      = (ushort*)alloc(128 * 256 * 2);
  ushort* Wc2      = (ushort*)alloc(128 * 256 * 2);
  float*  vecs     = (float*)alloc(1152 * 4);
  ushort* h0       = (ushort*)alloc((size_t)N_NODES * HD * 2);
  ushort* h1       = (ushort*)alloc((size_t)N_NODES * HD * 2);

  k_zero_probe<<<(N_NODES + 255) / 256 + 1, 256, 0, stream>>>((const ushort*)x, flag, cnt, cursor, total);
  k_prep_w<<<(128 * 256 + 255) / 256, 256, 0, stream>>>(flag, W_in, Wl1, Wr1, Wl2, Wr2, WtA, Wc1, Wc2,
                                                        b_in, kind_embed, ext_seed, bl1, gammap, betap, bl2, vecs);
  k_count<<<(N_EDGES + 255) / 256, 256, 0, stream>>>(dst, cnt);
  k_assign<<<(N_NODES + 255) / 256, 256, 0, stream>>>(cnt, rowstart, total);
  k_fill<<<(N_EDGES + 255) / 256, 256, 0, stream>>>(src, dst, rowstart, cursor, esrc);

  int gemm_grid = (N_NODES + 63) / 64;
  k_gemm_in<<<gemm_grid, 256, 0, stream>>>(flag, x, WtA, vecs, node_kind, h0);
  k_conv_fused<1><<<gemm_grid, 256, 0, stream>>>(flag, h0, rowstart, cnt, esrc, Wc1, vecs, (void*)h1);
  k_conv_fused<2><<<gemm_grid, 256, 0, stream>>>(flag, h1, rowstart, cnt, esrc, Wc2, vecs, d_out);
}

// Round 2
// 280.769 us; speedup vs baseline: 1.2360x; 1.2360x over previous
//
#include <hip/hip_runtime.h>
#include <stdint.h>

#define N_NODES 50000
#define N_EDGES 625000
#define DIN 256
#define HD 128
#define LN_EPS 1e-5f

typedef __attribute__((ext_vector_type(8))) short bvec8;
typedef __attribute__((ext_vector_type(4))) float fvec4;

__device__ inline float bf2f(ushort u){
  union { uint32_t u32; float f; } c; c.u32 = ((uint32_t)u) << 16; return c.f;
}
__device__ inline ushort f2bf(float f){
  union { float f; uint32_t u; } c; c.f = f;
  uint32_t u = c.u;
  return (ushort)((u + 0x7fffu + ((u >> 16) & 1u)) >> 16);
}
__device__ inline float rdany(const void* p, int i, int f32){
  return f32 ? ((const float*)p)[i] : bf2f(((const ushort*)p)[i]);
}

// ---------------- zero + dtype probe (merged) ----------------
__global__ void k_zero_probe(const ushort* __restrict__ x, int* __restrict__ flag,
                             int* cnt, int* cursor, int* total){
  if ((int)blockIdx.x == (int)gridDim.x - 1){
    __shared__ int red[256];
    int t = threadIdx.x;
    int c = 0;
    for (int j = 0; j < 8; j++){
      ushort u = x[t * 8 + j];
      int e = (u >> 7) & 0xff;
      if (e >= 0x88 || (e != 0 && e <= 0x70)) c++;
    }
    red[t] = c;
    __syncthreads();
    for (int off = 128; off > 0; off >>= 1){
      if (t < off) red[t] += red[t + off];
      __syncthreads();
    }
    if (t == 0) flag[0] = (red[0] > 100) ? 1 : 0;
    return;
  }
  int i = blockIdx.x * 256 + threadIdx.x;
  if (i < N_NODES){ cnt[i] = 0; cursor[i] = 0; }
  if (i == 0) total[0] = 0;
}

// ---------------- CSR build ----------------
__global__ void k_count(const int* __restrict__ dst, int* __restrict__ cnt){
  int e = blockIdx.x * 256 + threadIdx.x;
  if (e < N_EDGES) atomicAdd(&cnt[dst[e]], 1);
}

__global__ void k_assign(const int* __restrict__ cnt, int* __restrict__ rowstart,
                         int* __restrict__ total){
  int i = blockIdx.x * 256 + threadIdx.x;
  int lane = threadIdx.x & 63;
  int c = (i < N_NODES) ? cnt[i] : 0;
  int scan = c;
  #pragma unroll
  for (int m = 1; m < 64; m <<= 1){
    int v = __shfl_up(scan, m, 64);
    if (lane >= m) scan += v;
  }
  int wave_total = __shfl(scan, 63, 64);
  int base = 0;
  if (lane == 63) base = atomicAdd(total, wave_total);
  base = __shfl(base, 63, 64);
  if (i < N_NODES) rowstart[i] = base + scan - c;
}

__global__ void k_fill(const int* __restrict__ src, const int* __restrict__ dst,
                       const int* __restrict__ rowstart, int* __restrict__ cursor,
                       int* __restrict__ esrc){
  int e = blockIdx.x * 256 + threadIdx.x;
  if (e < N_EDGES){
    int d = dst[e];
    int pos = atomicAdd(&cursor[d], 1);
    esrc[rowstart[d] + pos] = src[e];
  }
}

// ---------------- weight prep: swizzle into MFMA fragment order ----------------
// chunk c = k0*8 + t; lane l's 8 elems are B-frag (n = t*16+(l&15), k = k0*32+(l>>4)*8+j)
__global__ void k_prep_w(const int* __restrict__ flag,
                         const void* __restrict__ W_in,
                         const void* __restrict__ Wl1, const void* __restrict__ Wr1,
                         const void* __restrict__ Wl2, const void* __restrict__ Wr2,
                         ushort* __restrict__ WtA, ushort* __restrict__ Wc1, ushort* __restrict__ Wc2,
                         const void* b_in, const void* kind_embed, const void* ext_seed,
                         const void* bl1, const void* gammap, const void* betap,
                         const void* bl2, float* __restrict__ vecs){
  int f32 = flag[0];
  int idx = blockIdx.x * 256 + threadIdx.x;
  if (idx < 128 * 256){
    int c   = idx >> 9;
    int lam = (idx >> 3) & 63;
    int j   = idx & 7;
    int k0  = c >> 3;
    int t   = c & 7;
    int n   = t * 16 + (lam & 15);
    int k   = k0 * 32 + (lam >> 4) * 8 + j;
    WtA[idx] = f2bf(rdany(W_in, k * 128 + n, f32));
    if (k < 128){
      Wc1[idx] = f2bf(rdany(Wl1, k * 128 + n, f32));
      Wc2[idx] = f2bf(rdany(Wl2, k * 128 + n, f32));
    } else {
      Wc1[idx] = f2bf(rdany(Wr1, (k - 128) * 128 + n, f32));
      Wc2[idx] = f2bf(rdany(Wr2, (k - 128) * 128 + n, f32));
    }
  }
  if (blockIdx.x == 0){
    for (int i = threadIdx.x; i < 1152; i += 256){
      float v;
      if (i < 128)       v = rdany(b_in, i, f32);
      else if (i < 512)  v = rdany(kind_embed, i - 128, f32);
      else if (i < 640)  v = rdany(ext_seed, i - 512, f32);
      else if (i < 768)  v = rdany(bl1, i - 640, f32);
      else if (i < 896)  v = rdany(gammap, i - 768, f32);
      else if (i < 1024) v = rdany(betap, i - 896, f32);
      else               v = rdany(bl2, i - 1024, f32);
      vecs[i] = v;
    }
  }
}

// ---------------- input GEMM: LDS-staged B ----------------
__global__ void __launch_bounds__(256) k_gemm_in(
    const int* __restrict__ flag, const void* __restrict__ xin,
    const ushort* __restrict__ WtA, const float* __restrict__ vecs,
    const int* __restrict__ node_kind, ushort* __restrict__ h0){
  __shared__ __align__(16) ushort sW[128 * 256];
  int f32 = flag[0];
  int tid  = threadIdx.x;
  int wave = tid >> 6;
  int lane = tid & 63;
  int quad = lane >> 4;
  int l16  = lane & 15;
  int rb = blockIdx.x * 64 + wave * 16;

  fvec4 acc[8];
  #pragma unroll
  for (int t = 0; t < 8; t++)
    #pragma unroll
    for (int i = 0; i < 4; i++) acc[t][i] = 0.f;

  int arow = rb + l16; if (arow >= N_NODES) arow = N_NODES - 1;
  const ushort* abf = (const ushort*)xin + (size_t)arow * DIN + quad * 8;
  const float*  af  = (const float*)xin + (size_t)arow * DIN + quad * 8;

  bvec8 a[8];
  if (f32){
    #pragma unroll
    for (int k0 = 0; k0 < 8; k0++){
      fvec4 lo = *(const fvec4*)(af + k0 * 32);
      fvec4 hi = *(const fvec4*)(af + k0 * 32 + 4);
      a[k0][0] = (short)f2bf(lo[0]); a[k0][1] = (short)f2bf(lo[1]);
      a[k0][2] = (short)f2bf(lo[2]); a[k0][3] = (short)f2bf(lo[3]);
      a[k0][4] = (short)f2bf(hi[0]); a[k0][5] = (short)f2bf(hi[1]);
      a[k0][6] = (short)f2bf(hi[2]); a[k0][7] = (short)f2bf(hi[3]);
    }
  } else {
    #pragma unroll
    for (int k0 = 0; k0 < 8; k0++) a[k0] = *(const bvec8*)(abf + k0 * 32);
  }

  #pragma unroll
  for (int it = 0; it < 16; it++){
    int off = it * 2048 + tid * 8;
    *(uint4*)(sW + off) = *(const uint4*)(WtA + off);
  }
  __syncthreads();

  #pragma unroll
  for (int k0 = 0; k0 < 8; k0++){
    #pragma unroll
    for (int t = 0; t < 8; t++){
      bvec8 b = *(const bvec8*)(sW + ((k0 * 8 + t) * 64 + lane) * 8);
      acc[t] = __builtin_amdgcn_mfma_f32_16x16x32_bf16(a[k0], b, acc[t], 0, 0, 0);
    }
  }

  const float* b_in  = vecs;
  const float* kinde = vecs + 128;
  const float* ext   = vecs + 512;
  #pragma unroll
  for (int i = 0; i < 4; i++){
    int row = rb + quad * 4 + i;
    if (row >= N_NODES) continue;
    int kind = node_kind[row];
    float extf = (kind != 0) ? 1.f : 0.f;
    #pragma unroll
    for (int t = 0; t < 8; t++){
      int col = t * 16 + l16;
      float v = acc[t][i] + b_in[col] + kinde[kind * HD + col] + extf * ext[col];
      h0[(size_t)row * HD + col] = f2bf(v);
    }
  }
}

// ---------------- standalone gather: one 16-lane quad per node ----------------
// High-occupancy latency hider: grid = 3125 blocks (12+ blocks/CU), no LDS,
// small VGPR footprint. Each quad streams its node's CSR edges 8 rows at a
// time (8x16B in flight per lane), f32 register accumulate, one coalesced
// 16B bf16 store of the scaled mean (h-layout, MFMA-frag ready).
__global__ void __launch_bounds__(256) k_gather(
    const ushort* __restrict__ h, const int* __restrict__ rowstart,
    const int* __restrict__ cnt, const int* __restrict__ esrc,
    ushort* __restrict__ agg){
  int tid  = threadIdx.x;
  int node = blockIdx.x * 16 + (tid >> 4);
  int l16  = tid & 15;
  if (node >= N_NODES) return;
  int b   = rowstart[node];
  int deg = cnt[node];
  int e   = b + deg;
  float acc[8];
  #pragma unroll
  for (int j = 0; j < 8; j++) acc[j] = 0.f;
  for (int i = b; i < e; i += 8){
    int idx[8];
    #pragma unroll
    for (int k = 0; k < 8; k++){
      int ee = i + k;
      idx[k] = esrc[ee < e ? ee : e - 1];
    }
    uint4 r[8];
    #pragma unroll
    for (int k = 0; k < 8; k++)
      r[k] = *(const uint4*)(h + (size_t)idx[k] * HD + l16 * 8);
    #pragma unroll
    for (int k = 0; k < 8; k++){
      if (i + k < e){
        const uint32_t* w = (const uint32_t*)&r[k];
        #pragma unroll
        for (int j = 0; j < 4; j++){
          acc[2*j]   += bf2f((ushort)(w[j] & 0xffffu));
          acc[2*j+1] += bf2f((ushort)(w[j] >> 16));
        }
      }
    }
  }
  float scale = (deg > 0) ? 1.f / (float)deg : 0.f;
  ushort ov[8];
  #pragma unroll
  for (int j = 0; j < 8; j++) ov[j] = f2bf(acc[j] * scale);
  *(uint4*)(agg + (size_t)node * HD + l16 * 8) = *(const uint4*)ov;
}

// ---------------- slim conv GEMM (agg precomputed) ----------------
// A-frags: agg half (K 0..127) from global agg, self half (K 128..255) from h.
// Weights in two 32KB half-stages over the same LDS, MFMA, fused epilogue.
template<int MODE>
__global__ void __launch_bounds__(256) k_conv(
    const int* __restrict__ flag, const ushort* __restrict__ h,
    const ushort* __restrict__ agg,
    const ushort* __restrict__ Wc, const float* __restrict__ vecs,
    void* __restrict__ outp){
  __shared__ __align__(16) ushort sW[16384];   // 32 KB
  int f32 = flag[0];
  int tid  = threadIdx.x;
  int wave = tid >> 6;
  int lane = tid & 63;
  int quad = lane >> 4;
  int l16  = lane & 15;
  int rb  = blockIdx.x * 64 + wave * 16;

  int arow = rb + l16; if (arow >= N_NODES) arow = N_NODES - 1;
  const ushort* ab = agg + (size_t)arow * HD + quad * 8;
  const ushort* hb = h   + (size_t)arow * HD + quad * 8;
  bvec8 a[8];
  #pragma unroll
  for (int j = 0; j < 4; j++) a[j]     = *(const bvec8*)(ab + j * 32);
  #pragma unroll
  for (int j = 0; j < 4; j++) a[4 + j] = *(const bvec8*)(hb + j * 32);

  fvec4 acc[8];
  #pragma unroll
  for (int t = 0; t < 8; t++)
    #pragma unroll
    for (int i = 0; i < 4; i++) acc[t][i] = 0.f;

  #pragma unroll
  for (int s = 0; s < 2; s++){
    if (s) __syncthreads();
    #pragma unroll
    for (int it = 0; it < 8; it++){
      int off = it * 2048 + tid * 8;
      *(uint4*)(sW + off) = *(const uint4*)(Wc + s * 16384 + off);
    }
    __syncthreads();
    #pragma unroll
    for (int k0 = 0; k0 < 4; k0++){
      #pragma unroll
      for (int t = 0; t < 8; t++){
        bvec8 b = *(const bvec8*)(sW + ((k0 * 8 + t) * 64 + lane) * 8);
        acc[t] = __builtin_amdgcn_mfma_f32_16x16x32_bf16(a[s * 4 + k0], b, acc[t], 0, 0, 0);
      }
    }
  }

  if (MODE == 1){
    const float* bias   = vecs + 640;
    const float* gammav = vecs + 768;
    const float* betav  = vecs + 896;
    float zv[8][4];
    float s1[4] = {0.f, 0.f, 0.f, 0.f};
    float s2[4] = {0.f, 0.f, 0.f, 0.f};
    #pragma unroll
    for (int t = 0; t < 8; t++){
      float bc = bias[t * 16 + l16];
      #pragma unroll
      for (int i = 0; i < 4; i++){
        float v = acc[t][i] + bc;
        zv[t][i] = v;
        s1[i] += v;
        s2[i] += v * v;
      }
    }
    #pragma unroll
    for (int m = 1; m < 16; m <<= 1){
      #pragma unroll
      for (int i = 0; i < 4; i++){
        s1[i] += __shfl_xor(s1[i], m, 64);
        s2[i] += __shfl_xor(s2[i], m, 64);
      }
    }
    float mu[4], rsv[4];
    #pragma unroll
    for (int i = 0; i < 4; i++){
      mu[i] = s1[i] * (1.f / 128.f);
      float var = s2[i] * (1.f / 128.f) - mu[i] * mu[i];
      rsv[i] = rsqrtf(var + LN_EPS);
    }
    ushort* ob = (ushort*)outp;
    #pragma unroll
    for (int t = 0; t < 8; t++){
      int col = t * 16 + l16;
      float g = gammav[col], bt = betav[col];
      #pragma unroll
      for (int i = 0; i < 4; i++){
        int row = rb + quad * 4 + i;
        if (row >= N_NODES) continue;
        float v = (zv[t][i] - mu[i]) * rsv[i] * g + bt;
        v = fmaxf(v, 0.f);
        ob[(size_t)row * HD + col] = f2bf(v);
      }
    }
  } else {
    const float* bias = vecs + 1024;
    #pragma unroll
    for (int t = 0; t < 8; t++){
      int col = t * 16 + l16;
      float bc = bias[col];
      #pragma unroll
      for (int i = 0; i < 4; i++){
        int row = rb + quad * 4 + i;
        if (row >= N_NODES) continue;
        float v = acc[t][i] + bc;
        if (f32) ((float*)outp)[(size_t)row * HD + col] = v;
        else     ((ushort*)outp)[(size_t)row * HD + col] = f2bf(v);
      }
    }
  }
}

extern "C" void kernel_launch(void* const* d_in, const int* in_sizes, int n_in,
                              void* d_out, int out_size, void* d_ws, size_t ws_size,
                              hipStream_t stream) {
  const void* x          = d_in[0];
  const int*  ei         = (const int*)d_in[1];
  const int*  node_kind  = (const int*)d_in[2];
  const void* W_in       = d_in[3];
  const void* b_in       = d_in[4];
  const void* kind_embed = d_in[5];
  const void* ext_seed   = d_in[6];
  const void* Wl1        = d_in[7];
  const void* bl1        = d_in[8];
  const void* Wr1        = d_in[9];
  const void* gammap     = d_in[10];
  const void* betap      = d_in[11];
  const void* Wl2        = d_in[12];
  const void* bl2        = d_in[13];
  const void* Wr2        = d_in[14];
  const int* src = ei;
  const int* dst = ei + N_EDGES;

  char* ws = (char*)d_ws;
  size_t off = 0;
  auto alloc = [&](size_t bytes) -> void* {
    void* p = ws + off;
    off += (bytes + 255) & ~(size_t)255;
    return p;
  };
  int*    flag     = (int*)alloc(256);
  int*    total    = (int*)alloc(256);
  int*    cnt      = (int*)alloc(N_NODES * 4);
  int*    cursor   = (int*)alloc(N_NODES * 4);
  int*    rowstart = (int*)alloc(N_NODES * 4);
  int*    esrc     = (int*)alloc(N_EDGES * 4);
  ushort* WtA      = (ushort*)alloc(128 * 256 * 2);
  ushort* Wc1      = (ushort*)alloc(128 * 256 * 2);
  ushort* Wc2      = (ushort*)alloc(128 * 256 * 2);
  float*  vecs     = (float*)alloc(1152 * 4);
  ushort* h0       = (ushort*)alloc((size_t)N_NODES * HD * 2);
  ushort* h1       = (ushort*)alloc((size_t)N_NODES * HD * 2);
  ushort* aggb     = (ushort*)alloc((size_t)N_NODES * HD * 2);

  k_zero_probe<<<(N_NODES + 255) / 256 + 1, 256, 0, stream>>>((const ushort*)x, flag, cnt, cursor, total);
  k_prep_w<<<(128 * 256 + 255) / 256, 256, 0, stream>>>(flag, W_in, Wl1, Wr1, Wl2, Wr2, WtA, Wc1, Wc2,
                                                        b_in, kind_embed, ext_seed, bl1, gammap, betap, bl2, vecs);
  k_count<<<(N_EDGES + 255) / 256, 256, 0, stream>>>(dst, cnt);
  k_assign<<<(N_NODES + 255) / 256, 256, 0, stream>>>(cnt, rowstart, total);
  k_fill<<<(N_EDGES + 255) / 256, 256, 0, stream>>>(src, dst, rowstart, cursor, esrc);

  int gemm_grid = (N_NODES + 63) / 64;
  int gath_grid = (N_NODES + 15) / 16;
  k_gemm_in<<<gemm_grid, 256, 0, stream>>>(flag, x, WtA, vecs, node_kind, h0);
  k_gather<<<gath_grid, 256, 0, stream>>>(h0, rowstart, cnt, esrc, aggb);
  k_conv<1><<<gemm_grid, 256, 0, stream>>>(flag, h0, aggb, Wc1, vecs, (void*)h1);
  k_gather<<<gath_grid, 256, 0, stream>>>(h1, rowstart, cnt, esrc, aggb);
  k_conv<2><<<gemm_grid, 256, 0, stream>>>(flag, h1, aggb, Wc2, vecs, d_out);
}

// Round 3
// 271.695 us; speedup vs baseline: 1.2773x; 1.0334x over previous
//
#include <hip/hip_runtime.h>
#include <stdint.h>

#define N_NODES 50000
#define N_EDGES 625000
#define DIN 256
#define HD 128
#define LN_EPS 1e-5f

#define GEMM_GRID 782      // (N_NODES+63)/64
#define EDGE_GRID 2442     // (N_EDGES+255)/256
#define NODE_GRID 196      // (N_NODES+255)/256

typedef __attribute__((ext_vector_type(8))) short bvec8;
typedef __attribute__((ext_vector_type(4))) float fvec4;

__device__ inline float bf2f(ushort u){
  union { uint32_t u32; float f; } c; c.u32 = ((uint32_t)u) << 16; return c.f;
}
__device__ inline ushort f2bf(float f){
  union { float f; uint32_t u; } c; c.f = f;
  uint32_t u = c.u;
  return (ushort)((u + 0x7fffu + ((u >> 16) & 1u)) >> 16);
}
__device__ inline float rdany(const void* p, int i, int f32){
  return f32 ? ((const float*)p)[i] : bf2f(((const ushort*)p)[i]);
}

// ---------------- zero CSR state ----------------
__global__ void k_zero(int* __restrict__ cnt, int* __restrict__ cursor,
                       int* __restrict__ total){
  int i = blockIdx.x * 256 + threadIdx.x;
  if (i < N_NODES){ cnt[i] = 0; cursor[i] = 0; }
  if (i == 0) total[0] = 0;
}

// ---------------- fused: weight prep (+inline dtype detect) || edge count ----------------
// blocks [0,128): weight swizzle into MFMA fragment order + vecs + flag
// blocks [128, 128+EDGE_GRID): histogram of dst into cnt
__global__ void k_prep_count(const ushort* __restrict__ x, int* __restrict__ flag,
                             const int* __restrict__ dst, int* __restrict__ cnt,
                             const void* __restrict__ W_in,
                             const void* __restrict__ Wl1, const void* __restrict__ Wr1,
                             const void* __restrict__ Wl2, const void* __restrict__ Wr2,
                             ushort* __restrict__ WtA, ushort* __restrict__ Wc1, ushort* __restrict__ Wc2,
                             const void* b_in, const void* kind_embed, const void* ext_seed,
                             const void* bl1, const void* gammap, const void* betap,
                             const void* bl2, float* __restrict__ vecs){
  if (blockIdx.x >= 128){
    int e = (blockIdx.x - 128) * 256 + threadIdx.x;
    if (e < N_EDGES) atomicAdd(&cnt[dst[e]], 1);
    return;
  }
  // inline dtype detect (same 4KB of x in every block; L2-hot)
  __shared__ int red[256];
  int t = threadIdx.x;
  {
    int c = 0;
    for (int j = 0; j < 8; j++){
      ushort u = x[t * 8 + j];
      int e = (u >> 7) & 0xff;
      if (e >= 0x88 || (e != 0 && e <= 0x70)) c++;
    }
    red[t] = c;
    __syncthreads();
    for (int off = 128; off > 0; off >>= 1){
      if (t < off) red[t] += red[t + off];
      __syncthreads();
    }
  }
  int f32 = (red[0] > 100) ? 1 : 0;
  if (blockIdx.x == 0 && t == 0) flag[0] = f32;

  int idx = blockIdx.x * 256 + t;
  {
    int c   = idx >> 9;
    int lam = (idx >> 3) & 63;
    int j   = idx & 7;
    int k0  = c >> 3;
    int tt  = c & 7;
    int n   = tt * 16 + (lam & 15);
    int k   = k0 * 32 + (lam >> 4) * 8 + j;
    WtA[idx] = f2bf(rdany(W_in, k * 128 + n, f32));
    if (k < 128){
      Wc1[idx] = f2bf(rdany(Wl1, k * 128 + n, f32));
      Wc2[idx] = f2bf(rdany(Wl2, k * 128 + n, f32));
    } else {
      Wc1[idx] = f2bf(rdany(Wr1, (k - 128) * 128 + n, f32));
      Wc2[idx] = f2bf(rdany(Wr2, (k - 128) * 128 + n, f32));
    }
  }
  if (blockIdx.x == 0){
    for (int i = t; i < 1152; i += 256){
      float v;
      if (i < 128)       v = rdany(b_in, i, f32);
      else if (i < 512)  v = rdany(kind_embed, i - 128, f32);
      else if (i < 640)  v = rdany(ext_seed, i - 512, f32);
      else if (i < 768)  v = rdany(bl1, i - 640, f32);
      else if (i < 896)  v = rdany(gammap, i - 768, f32);
      else if (i < 1024) v = rdany(betap, i - 896, f32);
      else               v = rdany(bl2, i - 1024, f32);
      vecs[i] = v;
    }
  }
}

// ---------------- CSR scan ----------------
__global__ void k_assign(const int* __restrict__ cnt, int* __restrict__ rowstart,
                         int* __restrict__ total){
  int i = blockIdx.x * 256 + threadIdx.x;
  int lane = threadIdx.x & 63;
  int c = (i < N_NODES) ? cnt[i] : 0;
  int scan = c;
  #pragma unroll
  for (int m = 1; m < 64; m <<= 1){
    int v = __shfl_up(scan, m, 64);
    if (lane >= m) scan += v;
  }
  int wave_total = __shfl(scan, 63, 64);
  int base = 0;
  if (lane == 63) base = atomicAdd(total, wave_total);
  base = __shfl(base, 63, 64);
  if (i < N_NODES) rowstart[i] = base + scan - c;
}

// ---------------- fused: input GEMM (32KB half-staged W) || CSR fill ----------------
// blocks [0, GEMM_GRID): x @ W_in + b + kind_embed + ext  -> h0  (bf16)
// blocks [GEMM_GRID, GEMM_GRID+EDGE_GRID): scatter edges into CSR esrc
__global__ void __launch_bounds__(256) k_gemm_fill(
    const int* __restrict__ flag, const void* __restrict__ xin,
    const ushort* __restrict__ WtA, const float* __restrict__ vecs,
    const int* __restrict__ node_kind, ushort* __restrict__ h0,
    const int* __restrict__ src, const int* __restrict__ dst,
    const int* __restrict__ rowstart, int* __restrict__ cursor,
    int* __restrict__ esrc){
  __shared__ __align__(16) ushort sW[16384];   // 32 KB (half of WtA at a time)
  if (blockIdx.x >= GEMM_GRID){
    int e = (blockIdx.x - GEMM_GRID) * 256 + threadIdx.x;
    if (e < N_EDGES){
      int d = dst[e];
      int pos = atomicAdd(&cursor[d], 1);
      esrc[rowstart[d] + pos] = src[e];
    }
    return;
  }
  int f32 = flag[0];
  int tid  = threadIdx.x;
  int wave = tid >> 6;
  int lane = tid & 63;
  int quad = lane >> 4;
  int l16  = lane & 15;
  int rb = blockIdx.x * 64 + wave * 16;

  fvec4 acc[8];
  #pragma unroll
  for (int t = 0; t < 8; t++)
    #pragma unroll
    for (int i = 0; i < 4; i++) acc[t][i] = 0.f;

  int arow = rb + l16; if (arow >= N_NODES) arow = N_NODES - 1;
  const ushort* abf = (const ushort*)xin + (size_t)arow * DIN + quad * 8;
  const float*  af  = (const float*)xin + (size_t)arow * DIN + quad * 8;

  bvec8 a[8];
  if (f32){
    #pragma unroll
    for (int k0 = 0; k0 < 8; k0++){
      fvec4 lo = *(const fvec4*)(af + k0 * 32);
      fvec4 hi = *(const fvec4*)(af + k0 * 32 + 4);
      a[k0][0] = (short)f2bf(lo[0]); a[k0][1] = (short)f2bf(lo[1]);
      a[k0][2] = (short)f2bf(lo[2]); a[k0][3] = (short)f2bf(lo[3]);
      a[k0][4] = (short)f2bf(hi[0]); a[k0][5] = (short)f2bf(hi[1]);
      a[k0][6] = (short)f2bf(hi[2]); a[k0][7] = (short)f2bf(hi[3]);
    }
  } else {
    #pragma unroll
    for (int k0 = 0; k0 < 8; k0++) a[k0] = *(const bvec8*)(abf + k0 * 32);
  }

  #pragma unroll
  for (int s = 0; s < 2; s++){
    if (s) __syncthreads();
    #pragma unroll
    for (int it = 0; it < 8; it++){
      int off = it * 2048 + tid * 8;
      *(uint4*)(sW + off) = *(const uint4*)(WtA + s * 16384 + off);
    }
    __syncthreads();
    #pragma unroll
    for (int k0 = 0; k0 < 4; k0++){
      #pragma unroll
      for (int t = 0; t < 8; t++){
        bvec8 b = *(const bvec8*)(sW + ((k0 * 8 + t) * 64 + lane) * 8);
        acc[t] = __builtin_amdgcn_mfma_f32_16x16x32_bf16(a[s * 4 + k0], b, acc[t], 0, 0, 0);
      }
    }
  }

  const float* b_in  = vecs;
  const float* kinde = vecs + 128;
  const float* ext   = vecs + 512;
  #pragma unroll
  for (int i = 0; i < 4; i++){
    int row = rb + quad * 4 + i;
    if (row >= N_NODES) continue;
    int kind = node_kind[row];
    float extf = (kind != 0) ? 1.f : 0.f;
    #pragma unroll
    for (int t = 0; t < 8; t++){
      int col = t * 16 + l16;
      float v = acc[t][i] + b_in[col] + kinde[kind * HD + col] + extf * ext[col];
      h0[(size_t)row * HD + col] = f2bf(v);
    }
  }
}

// ---------------- standalone gather: one 16-lane quad per node ----------------
// 16 rows in flight per lane (deg mean 12.5 -> usually one batch; clamped
// tail loads re-hit the same line). f32 register accumulate, one coalesced
// 16B bf16 store of the scaled mean (h-layout, MFMA-frag ready).
__global__ void __launch_bounds__(256) k_gather(
    const ushort* __restrict__ h, const int* __restrict__ rowstart,
    const int* __restrict__ cnt, const int* __restrict__ esrc,
    ushort* __restrict__ agg){
  int tid  = threadIdx.x;
  int node = blockIdx.x * 16 + (tid >> 4);
  int l16  = tid & 15;
  if (node >= N_NODES) return;
  int b   = rowstart[node];
  int deg = cnt[node];
  int e   = b + deg;
  float acc[8];
  #pragma unroll
  for (int j = 0; j < 8; j++) acc[j] = 0.f;
  for (int i = b; i < e; i += 16){
    int idx[16];
    #pragma unroll
    for (int k = 0; k < 16; k++){
      int ee = i + k;
      idx[k] = esrc[ee < e ? ee : e - 1];
    }
    uint4 r[16];
    #pragma unroll
    for (int k = 0; k < 16; k++)
      r[k] = *(const uint4*)(h + (size_t)idx[k] * HD + l16 * 8);
    #pragma unroll
    for (int k = 0; k < 16; k++){
      if (i + k < e){
        const uint32_t* w = (const uint32_t*)&r[k];
        #pragma unroll
        for (int j = 0; j < 4; j++){
          acc[2*j]   += bf2f((ushort)(w[j] & 0xffffu));
          acc[2*j+1] += bf2f((ushort)(w[j] >> 16));
        }
      }
    }
  }
  float scale = (deg > 0) ? 1.f / (float)deg : 0.f;
  ushort ov[8];
  #pragma unroll
  for (int j = 0; j < 8; j++) ov[j] = f2bf(acc[j] * scale);
  *(uint4*)(agg + (size_t)node * HD + l16 * 8) = *(const uint4*)ov;
}

// ---------------- slim conv GEMM (agg precomputed) ----------------
// A-frags: agg half (K 0..127) from global agg, self half (K 128..255) from h.
// Weights in two 32KB half-stages over the same LDS, MFMA, fused epilogue.
template<int MODE>
__global__ void __launch_bounds__(256) k_conv(
    const int* __restrict__ flag, const ushort* __restrict__ h,
    const ushort* __restrict__ agg,
    const ushort* __restrict__ Wc, const float* __restrict__ vecs,
    void* __restrict__ outp){
  __shared__ __align__(16) ushort sW[16384];   // 32 KB
  int f32 = flag[0];
  int tid  = threadIdx.x;
  int wave = tid >> 6;
  int lane = tid & 63;
  int quad = lane >> 4;
  int l16  = lane & 15;
  int rb  = blockIdx.x * 64 + wave * 16;

  int arow = rb + l16; if (arow >= N_NODES) arow = N_NODES - 1;
  const ushort* ab = agg + (size_t)arow * HD + quad * 8;
  const ushort* hb = h   + (size_t)arow * HD + quad * 8;
  bvec8 a[8];
  #pragma unroll
  for (int j = 0; j < 4; j++) a[j]     = *(const bvec8*)(ab + j * 32);
  #pragma unroll
  for (int j = 0; j < 4; j++) a[4 + j] = *(const bvec8*)(hb + j * 32);

  fvec4 acc[8];
  #pragma unroll
  for (int t = 0; t < 8; t++)
    #pragma unroll
    for (int i = 0; i < 4; i++) acc[t][i] = 0.f;

  #pragma unroll
  for (int s = 0; s < 2; s++){
    if (s) __syncthreads();
    #pragma unroll
    for (int it = 0; it < 8; it++){
      int off = it * 2048 + tid * 8;
      *(uint4*)(sW + off) = *(const uint4*)(Wc + s * 16384 + off);
    }
    __syncthreads();
    #pragma unroll
    for (int k0 = 0; k0 < 4; k0++){
      #pragma unroll
      for (int t = 0; t < 8; t++){
        bvec8 b = *(const bvec8*)(sW + ((k0 * 8 + t) * 64 + lane) * 8);
        acc[t] = __builtin_amdgcn_mfma_f32_16x16x32_bf16(a[s * 4 + k0], b, acc[t], 0, 0, 0);
      }
    }
  }

  if (MODE == 1){
    const float* bias   = vecs + 640;
    const float* gammav = vecs + 768;
    const float* betav  = vecs + 896;
    float zv[8][4];
    float s1[4] = {0.f, 0.f, 0.f, 0.f};
    float s2[4] = {0.f, 0.f, 0.f, 0.f};
    #pragma unroll
    for (int t = 0; t < 8; t++){
      float bc = bias[t * 16 + l16];
      #pragma unroll
      for (int i = 0; i < 4; i++){
        float v = acc[t][i] + bc;
        zv[t][i] = v;
        s1[i] += v;
        s2[i] += v * v;
      }
    }
    #pragma unroll
    for (int m = 1; m < 16; m <<= 1){
      #pragma unroll
      for (int i = 0; i < 4; i++){
        s1[i] += __shfl_xor(s1[i], m, 64);
        s2[i] += __shfl_xor(s2[i], m, 64);
      }
    }
    float mu[4], rsv[4];
    #pragma unroll
    for (int i = 0; i < 4; i++){
      mu[i] = s1[i] * (1.f / 128.f);
      float var = s2[i] * (1.f / 128.f) - mu[i] * mu[i];
      rsv[i] = rsqrtf(var + LN_EPS);
    }
    ushort* ob = (ushort*)outp;
    #pragma unroll
    for (int t = 0; t < 8; t++){
      int col = t * 16 + l16;
      float g = gammav[col], bt = betav[col];
      #pragma unroll
      for (int i = 0; i < 4; i++){
        int row = rb + quad * 4 + i;
        if (row >= N_NODES) continue;
        float v = (zv[t][i] - mu[i]) * rsv[i] * g + bt;
        v = fmaxf(v, 0.f);
        ob[(size_t)row * HD + col] = f2bf(v);
      }
    }
  } else {
    const float* bias = vecs + 1024;
    #pragma unroll
    for (int t = 0; t < 8; t++){
      int col = t * 16 + l16;
      float bc = bias[col];
      #pragma unroll
      for (int i = 0; i < 4; i++){
        int row = rb + quad * 4 + i;
        if (row >= N_NODES) continue;
        float v = acc[t][i] + bc;
        if (f32) ((float*)outp)[(size_t)row * HD + col] = v;
        else     ((ushort*)outp)[(size_t)row * HD + col] = f2bf(v);
      }
    }
  }
}

extern "C" void kernel_launch(void* const* d_in, const int* in_sizes, int n_in,
                              void* d_out, int out_size, void* d_ws, size_t ws_size,
                              hipStream_t stream) {
  const void* x          = d_in[0];
  const int*  ei         = (const int*)d_in[1];
  const int*  node_kind  = (const int*)d_in[2];
  const void* W_in       = d_in[3];
  const void* b_in       = d_in[4];
  const void* kind_embed = d_in[5];
  const void* ext_seed   = d_in[6];
  const void* Wl1        = d_in[7];
  const void* bl1        = d_in[8];
  const void* Wr1        = d_in[9];
  const void* gammap     = d_in[10];
  const void* betap      = d_in[11];
  const void* Wl2        = d_in[12];
  const void* bl2        = d_in[13];
  const void* Wr2        = d_in[14];
  const int* src = ei;
  const int* dst = ei + N_EDGES;

  char* ws = (char*)d_ws;
  size_t off = 0;
  auto alloc = [&](size_t bytes) -> void* {
    void* p = ws + off;
    off += (bytes + 255) & ~(size_t)255;
    return p;
  };
  int*    flag     = (int*)alloc(256);
  int*    total    = (int*)alloc(256);
  int*    cnt      = (int*)alloc(N_NODES * 4);
  int*    cursor   = (int*)alloc(N_NODES * 4);
  int*    rowstart = (int*)alloc(N_NODES * 4);
  int*    esrc     = (int*)alloc(N_EDGES * 4);
  ushort* WtA      = (ushort*)alloc(128 * 256 * 2);
  ushort* Wc1      = (ushort*)alloc(128 * 256 * 2);
  ushort* Wc2      = (ushort*)alloc(128 * 256 * 2);
  float*  vecs     = (float*)alloc(1152 * 4);
  ushort* h0       = (ushort*)alloc((size_t)N_NODES * HD * 2);
  ushort* h1       = (ushort*)alloc((size_t)N_NODES * HD * 2);
  ushort* aggb     = (ushort*)alloc((size_t)N_NODES * HD * 2);

  k_zero<<<NODE_GRID, 256, 0, stream>>>(cnt, cursor, total);
  k_prep_count<<<128 + EDGE_GRID, 256, 0, stream>>>((const ushort*)x, flag, dst, cnt,
                                                    W_in, Wl1, Wr1, Wl2, Wr2, WtA, Wc1, Wc2,
                                                    b_in, kind_embed, ext_seed, bl1, gammap, betap, bl2, vecs);
  k_assign<<<NODE_GRID, 256, 0, stream>>>(cnt, rowstart, total);
  k_gemm_fill<<<GEMM_GRID + EDGE_GRID, 256, 0, stream>>>(flag, x, WtA, vecs, node_kind, h0,
                                                         src, dst, rowstart, cursor, esrc);

  int gath_grid = (N_NODES + 15) / 16;
  k_gather<<<gath_grid, 256, 0, stream>>>(h0, rowstart, cnt, esrc, aggb);
  k_conv<1><<<GEMM_GRID, 256, 0, stream>>>(flag, h0, aggb, Wc1, vecs, (void*)h1);
  k_gather<<<gath_grid, 256, 0, stream>>>(h1, rowstart, cnt, esrc, aggb);
  k_conv<2><<<GEMM_GRID, 256, 0, stream>>>(flag, h1, aggb, Wc2, vecs, d_out);
}